// Round 1
// 574.632 us; speedup vs baseline: 1.0165x; 1.0165x over previous
//
#include <hip/hip_runtime.h>
#include <math.h>

// Shapes (fixed)
#define BB 2
#define HH 16
#define SS 2048
#define DD 1024
#define DK 64
#define BHS (BB*HH*SS)          // 65536
#define QSCALE 0.04508422f      // log2(e)/sqrt(1024): folded into q so softmax uses exp2

typedef short  bf16x8  __attribute__((ext_vector_type(8)));
typedef float  floatx4 __attribute__((ext_vector_type(4)));
typedef unsigned short u16;

#define MFMA(a,b,c) __builtin_amdgcn_mfma_f32_16x16x32_bf16((a),(b),(c),0,0,0)

// hardware packed conversion: dst.lo = bf16(lo), dst.hi = bf16(hi), RNE
__device__ __forceinline__ unsigned cvt_pk_bf16(float lo, float hi) {
    unsigned r;
    asm("v_cvt_pk_bf16_f32 %0, %1, %2" : "=v"(r) : "v"(lo), "v"(hi));
    return r;
}
__device__ __forceinline__ bf16x8 ldfrag(const u16* p) {
    union { uint4 u; bf16x8 b; } c;
    c.u = *(const uint4*)p;
    return c.b;
}
__device__ __forceinline__ void stbf4(u16* p, float4 t) {  // 4xf32 -> 4xbf16, 8B store
    union { unsigned u[2]; uint2 v; } c;
    c.u[0] = cvt_pk_bf16(t.x, t.y);
    c.u[1] = cvt_pk_bf16(t.z, t.w);
    *(uint2*)p = c.v;
}
// 4 f32 -> bf16 at p[0], p[16], p[32], p[48]  (C-fragment col stride 16)
__device__ __forceinline__ void st4s(u16* p, float a, float b, float c, float d) {
    unsigned x = cvt_pk_bf16(a, b), y = cvt_pk_bf16(c, d);
    p[0]  = (u16)x; p[16] = (u16)(x >> 16);
    p[32] = (u16)y; p[48] = (u16)(y >> 16);
}

// ---------------------------------------------------------------------------
// Kernel 0: one-shot weight conversion fp32->bf16.
// wqkv_bf rows 0-63 = wq, 64-127 = wk, 128-191 = wv; wo_bf = wo.
// Removes the 1024x-redundant per-block weight conversion from qkv/out proj.
// ---------------------------------------------------------------------------
#define WQKV_CHUNKS (192*1024/4)     // 49152 float4 chunks
#define WO_CHUNKS   (1024*1024/4)    // 262144
__global__ __launch_bounds__(256) void convert_w(
    const float* __restrict__ wq, const float* __restrict__ wk,
    const float* __restrict__ wv, const float* __restrict__ wo,
    u16* __restrict__ wqkv, u16* __restrict__ wo_bf)
{
    int i = blockIdx.x * 256 + threadIdx.x;
    if (i < WQKV_CHUNKS) {
        int r = i >> 8;            // row 0..191 (256 float4 per row)
        int c = i & 255;
        const float* src = (r < 64) ? wq : ((r < 128) ? wk : wv);
        float4 t = *(const float4*)(src + (size_t)(r & 63) * DD + c * 4);
        stbf4(wqkv + (size_t)r * DD + c * 4, t);
    } else if (i < WQKV_CHUNKS + WO_CHUNKS) {
        int j = i - WQKV_CHUNKS;
        float4 t = *(const float4*)(wo + (size_t)j * 4);
        stbf4(wo_bf + (size_t)j * 4, t);
    }
}

// ---------------------------------------------------------------------------
// Kernel 1: QKV projection, bf16 MFMA.
// x [BHS,1024] fp32 -> q (pre-scaled by QSCALE), k bf16 [BHS,64]; v TRANSPOSED
// per head: vT[(bh*64+dk)*2048 + s], via LDS transpose in the epilogue.
// Weights staged from pre-converted bf16 (pure uint4 copies, no VALU convert).
// ---------------------------------------------------------------------------
__global__ __launch_bounds__(256) void qkv_proj(
    const float* __restrict__ x, const u16* __restrict__ wqkv,
    u16* __restrict__ q, u16* __restrict__ k, u16* __restrict__ vT)
{
    __shared__ __align__(16) u16 Xs[64][72];    // 9216 B (reused as Vbuf)
    __shared__ __align__(16) u16 Ws[192][72];   // 27648 B
    const int tid  = threadIdx.x;
    const int w    = tid >> 6;
    const int lane = tid & 63;
    const int quad = lane >> 4;
    const int l16  = lane & 15;
    const int rowbase = blockIdx.x * 64;

    floatx4 acc[12];
#pragma unroll
    for (int n = 0; n < 12; ++n) acc[n] = (floatx4){0.f,0.f,0.f,0.f};

    for (int k0 = 0; k0 < DD; k0 += 64) {
        // stage X tile 64x64 fp32->bf16 via cvt_pk (1024 float4 chunks, 4/thread)
#pragma unroll
        for (int it = 0; it < 4; ++it) {
            int li = tid + it * 256;
            int r  = li >> 4;
            int c4 = li & 15;
            float4 t = *(const float4*)(x + (size_t)(rowbase + r) * DD + k0 + c4 * 4);
            stbf4(&Xs[r][c4 * 4], t);
        }
        // stage W tile 192x64 bf16 (1536 uint4 chunks, 6/thread) — plain copy
#pragma unroll
        for (int it = 0; it < 6; ++it) {
            int li = tid + it * 256;
            int r  = li >> 3;
            int c8 = li & 7;
            *(uint4*)&Ws[r][c8 * 8] =
                *(const uint4*)(wqkv + (size_t)r * DD + k0 + c8 * 8);
        }
        __syncthreads();

        bf16x8 a0 = ldfrag(&Xs[w * 16 + l16][quad * 8]);
        bf16x8 a1 = ldfrag(&Xs[w * 16 + l16][32 + quad * 8]);
#pragma unroll
        for (int n = 0; n < 12; ++n) {
            bf16x8 b0 = ldfrag(&Ws[n * 16 + l16][quad * 8]);
            bf16x8 b1 = ldfrag(&Ws[n * 16 + l16][32 + quad * 8]);
            acc[n] = MFMA(a0, b0, acc[n]);
            acc[n] = MFMA(a1, b1, acc[n]);
        }
        __syncthreads();
    }

    // epilogue: D row = w*16 + quad*4 + r (block-local), col = n*16 + l16
#pragma unroll
    for (int r = 0; r < 4; ++r) {
        int row = w * 16 + quad * 4 + r;
        size_t m = (size_t)(rowbase + row);
        st4s(&q[m * DK + l16], acc[0][r] * QSCALE, acc[1][r] * QSCALE,
                               acc[2][r] * QSCALE, acc[3][r] * QSCALE);
        st4s(&k[m * DK + l16], acc[4][r], acc[5][r], acc[6][r], acc[7][r]);
    }
    // v: transpose through LDS (Xs dead after last barrier), write vT coalesced
    u16 (*Vbuf)[72] = Xs;
#pragma unroll
    for (int r = 0; r < 4; ++r) {
        int row = w * 16 + quad * 4 + r;
        st4s(&Vbuf[row][l16], acc[8][r], acc[9][r], acc[10][r], acc[11][r]);
    }
    __syncthreads();
    {
        const int dk = tid >> 2;            // 0..63
        const int sc = (tid & 3) * 16;      // s-chunk
        const int bh = rowbase >> 11;       // rowbase / 2048
        const int s0 = rowbase & 2047;
        union { u16 s[16]; uint4 u[2]; } t;
#pragma unroll
        for (int u = 0; u < 16; ++u) t.s[u] = Vbuf[sc + u][dk];
        uint4* dst = (uint4*)(vT + ((size_t)(bh * DK + dk)) * SS + s0 + sc);
        dst[0] = t.u[0];
        dst[1] = t.u[1];
    }
}

// ---------------------------------------------------------------------------
// Kernel 2: flash attention, bf16 MFMA, online softmax in log2 domain.
// q is pre-scaled by log2(e)/sqrt(1024) -> raw v_exp_f32, no scale muls.
// Defer-max (THR=8): skip O-rescale when the tile max doesn't grow.
// ---------------------------------------------------------------------------
__global__ __launch_bounds__(256) void flash_attn(
    const u16* __restrict__ q, const u16* __restrict__ k,
    const u16* __restrict__ vT, u16* __restrict__ ao)
{
    __shared__ __align__(16) u16 Qs[64][72];
    __shared__ __align__(16) u16 Ks[64][72];
    __shared__ __align__(16) u16 Vt[64][72];       // Vt[dk][t]
    __shared__ __align__(16) u16 Ps[4][16][72];    // per-wave P tile
    const int tid  = threadIdx.x;
    const int w    = tid >> 6;
    const int lane = tid & 63;
    const int quad = lane >> 4;
    const int l16  = lane & 15;
    const int qt   = blockIdx.x;
    const int bh   = blockIdx.y;
    const size_t kbase = (size_t)bh * SS * DK;     // q,k layout [bh*S + t][64]
    const size_t vbase = (size_t)bh * DK * SS;     // vT layout [bh*64 + dk][S]

    // load Q tile once (512 uint4 chunks, 2/thread)
#pragma unroll
    for (int it = 0; it < 2; ++it) {
        int li = tid + it * 256;
        int r  = li >> 3;
        int c8 = li & 7;
        *(uint4*)&Qs[r][c8 * 8] =
            *(const uint4*)(q + kbase + (size_t)(qt * 64 + r) * DK + c8 * 8);
    }

    float m_i[4], l_i[4];
    floatx4 acc_o[4];
#pragma unroll
    for (int r = 0; r < 4; ++r) { m_i[r] = -INFINITY; l_i[r] = 0.f; }
#pragma unroll
    for (int n = 0; n < 4; ++n) acc_o[n] = (floatx4){0.f,0.f,0.f,0.f};
    __syncthreads();

    for (int kt = 0; kt < SS / 64; ++kt) {
        // stage K tile [64 t][64 dk] and Vt tile [64 dk][64 t]
#pragma unroll
        for (int it = 0; it < 2; ++it) {
            int li = tid + it * 256;
            int r  = li >> 3;
            int c8 = li & 7;
            *(uint4*)&Ks[r][c8 * 8] =
                *(const uint4*)(k + kbase + (size_t)(kt * 64 + r) * DK + c8 * 8);
            *(uint4*)&Vt[r][c8 * 8] =
                *(const uint4*)(vT + vbase + (size_t)r * SS + kt * 64 + c8 * 8);
        }
        __syncthreads();

        // scores (log2 units): wave rows w*16.., cols kt*64..
        floatx4 sc[4];
        __builtin_amdgcn_s_setprio(1);
        {
            bf16x8 a0 = ldfrag(&Qs[w * 16 + l16][quad * 8]);
            bf16x8 a1 = ldfrag(&Qs[w * 16 + l16][32 + quad * 8]);
#pragma unroll
            for (int n = 0; n < 4; ++n) {
                sc[n] = (floatx4){0.f,0.f,0.f,0.f};
                bf16x8 b0 = ldfrag(&Ks[n * 16 + l16][quad * 8]);
                bf16x8 b1 = ldfrag(&Ks[n * 16 + l16][32 + quad * 8]);
                sc[n] = MFMA(a0, b0, sc[n]);
                sc[n] = MFMA(a1, b1, sc[n]);
            }
        }
        __builtin_amdgcn_s_setprio(0);

        // row maxima (row = quad*4+r), 16-lane butterfly within quad
        float rmx[4];
#pragma unroll
        for (int r = 0; r < 4; ++r) {
            float rm = fmaxf(fmaxf(sc[0][r], sc[1][r]), fmaxf(sc[2][r], sc[3][r]));
#pragma unroll
            for (int off = 1; off < 16; off <<= 1)
                rm = fmaxf(rm, __shfl_xor(rm, off, 64));
            rmx[r] = rm;
        }
        // defer-max: only rescale when some row max grew by > 8 (log2 units)
        int ok = (rmx[0] <= m_i[0] + 8.f) & (rmx[1] <= m_i[1] + 8.f) &
                 (rmx[2] <= m_i[2] + 8.f) & (rmx[3] <= m_i[3] + 8.f);
        if (!__all(ok)) {
#pragma unroll
            for (int r = 0; r < 4; ++r) {
                float mnew  = fmaxf(m_i[r], rmx[r]);
                float alpha = __builtin_amdgcn_exp2f(m_i[r] - mnew);
#pragma unroll
                for (int n = 0; n < 4; ++n) acc_o[n][r] *= alpha;
                l_i[r] *= alpha;
                m_i[r]  = mnew;
            }
        }
        // P = exp2(S - m), row sums, P -> LDS (bf16 via cvt_pk)
#pragma unroll
        for (int r = 0; r < 4; ++r) {
            float mi = m_i[r];
            float p0 = __builtin_amdgcn_exp2f(sc[0][r] - mi);
            float p1 = __builtin_amdgcn_exp2f(sc[1][r] - mi);
            float p2 = __builtin_amdgcn_exp2f(sc[2][r] - mi);
            float p3 = __builtin_amdgcn_exp2f(sc[3][r] - mi);
            float rs = (p0 + p1) + (p2 + p3);
#pragma unroll
            for (int off = 1; off < 16; off <<= 1)
                rs += __shfl_xor(rs, off, 64);
            l_i[r] += rs;
            st4s(&Ps[w][quad * 4 + r][l16], p0, p1, p2, p3);
        }
        // Ps is per-wave private: no barrier needed (compiler inserts lgkmcnt)

        // PV: O += P[16 x 64t] * V[64t x 64dk]
        __builtin_amdgcn_s_setprio(1);
#pragma unroll
        for (int kc = 0; kc < 2; ++kc) {
            bf16x8 a = ldfrag(&Ps[w][l16][kc * 32 + quad * 8]);
#pragma unroll
            for (int n = 0; n < 4; ++n) {
                bf16x8 b = ldfrag(&Vt[n * 16 + l16][kc * 32 + quad * 8]);
                acc_o[n] = MFMA(a, b, acc_o[n]);
            }
        }
        __builtin_amdgcn_s_setprio(0);
        __syncthreads();   // Ks/Vt consumed; safe to restage
    }

    // epilogue -> ao[B,S,H*64] bf16
    const int b = bh >> 4, h = bh & 15;
#pragma unroll
    for (int r = 0; r < 4; ++r) {
        int srow = qt * 64 + w * 16 + quad * 4 + r;
        float rl = __builtin_amdgcn_rcpf(l_i[r]);
        size_t base = ((size_t)(b * SS + srow)) * (HH * DK) + h * 64;
        st4s(&ao[base + l16], acc_o[0][r] * rl, acc_o[1][r] * rl,
                              acc_o[2][r] * rl, acc_o[3][r] * rl);
    }
}

// ---------------------------------------------------------------------------
// Kernel 3: output projection, bf16 MFMA. out[4096,1024] = ao @ wo^T (fp32 out).
// B staged from pre-converted bf16 wo (pure copies).
// ---------------------------------------------------------------------------
__global__ __launch_bounds__(256) void out_proj(
    const u16* __restrict__ ao, const u16* __restrict__ wo_bf,
    float* __restrict__ out)
{
    __shared__ __align__(16) u16 As[64][72];
    __shared__ __align__(16) u16 Bs[64][72];
    const int tid  = threadIdx.x;
    const int w    = tid >> 6;
    const int lane = tid & 63;
    const int quad = lane >> 4;
    const int l16  = lane & 15;
    const int mt = blockIdx.y;
    const int nt = blockIdx.x;

    floatx4 acc[4];
#pragma unroll
    for (int n = 0; n < 4; ++n) acc[n] = (floatx4){0.f,0.f,0.f,0.f};

    for (int k0 = 0; k0 < DD; k0 += 64) {
#pragma unroll
        for (int it = 0; it < 2; ++it) {
            int li = tid + it * 256;
            int r  = li >> 3;
            int c8 = li & 7;
            *(uint4*)&As[r][c8 * 8] =
                *(const uint4*)(ao + (size_t)(mt * 64 + r) * DD + k0 + c8 * 8);
            *(uint4*)&Bs[r][c8 * 8] =
                *(const uint4*)(wo_bf + (size_t)(nt * 64 + r) * DD + k0 + c8 * 8);
        }
        __syncthreads();

        bf16x8 a0 = ldfrag(&As[w * 16 + l16][quad * 8]);
        bf16x8 a1 = ldfrag(&As[w * 16 + l16][32 + quad * 8]);
#pragma unroll
        for (int n = 0; n < 4; ++n) {
            bf16x8 b0 = ldfrag(&Bs[n * 16 + l16][quad * 8]);
            bf16x8 b1 = ldfrag(&Bs[n * 16 + l16][32 + quad * 8]);
            acc[n] = MFMA(a0, b0, acc[n]);
            acc[n] = MFMA(a1, b1, acc[n]);
        }
        __syncthreads();
    }

#pragma unroll
    for (int r = 0; r < 4; ++r) {
        int row = mt * 64 + w * 16 + quad * 4 + r;
#pragma unroll
        for (int n = 0; n < 4; ++n)
            out[(size_t)row * DD + nt * 64 + n * 16 + l16] = acc[n][r];
    }
}

// ---------------------------------------------------------------------------
extern "C" void kernel_launch(void* const* d_in, const int* in_sizes, int n_in,
                              void* d_out, int out_size, void* d_ws, size_t ws_size,
                              hipStream_t stream) {
    const float* x  = (const float*)d_in[0];
    const float* wq = (const float*)d_in[1];
    const float* wk = (const float*)d_in[2];
    const float* wv = (const float*)d_in[3];
    const float* wo = (const float*)d_in[4];
    float* out = (float*)d_out;

    // workspace (bf16): q,k [BHS,64]; vT [B,H,64,S]; ao [B,S,1024];
    // wqkv_bf [192,1024]; wo_bf [1024,1024]   = ~36 MB
    u16* q    = (u16*)d_ws;
    u16* k    = q    + (size_t)BHS * DK;
    u16* vT   = k    + (size_t)BHS * DK;
    u16* ao   = vT   + (size_t)BHS * DK;
    u16* wqkv = ao   + (size_t)BHS * DK;
    u16* wo_bf = wqkv + (size_t)192 * DD;

    convert_w<<<dim3((WQKV_CHUNKS + WO_CHUNKS) / 256), dim3(256), 0, stream>>>(
        wq, wk, wv, wo, wqkv, wo_bf);
    qkv_proj<<<dim3(BHS / 64), dim3(256), 0, stream>>>(x, wqkv, q, k, vT);
    flash_attn<<<dim3(SS / 64, BB * HH), dim3(256), 0, stream>>>(q, k, vT, ao);
    out_proj<<<dim3(DD / 64, (BB * SS) / 64), dim3(256), 0, stream>>>(ao, wo_bf, out);
}